// Round 1
// baseline (475.302 us; speedup 1.0000x reference)
//
#include <hip/hip_runtime.h>
#include <stdint.h>

#define FD    512
#define SEQ   2048
#define NHALF 8192
#define NTOT  16384
#define QKVN  1536

typedef unsigned short u16;
typedef __attribute__((ext_vector_type(8))) short short8;
typedef __attribute__((ext_vector_type(4))) float f32x4;

__device__ __forceinline__ u16 f2bf(float f){
  union { float f; uint32_t i; } v; v.f = f;
  uint32_t r = v.i + 0x7FFFu + ((v.i >> 16) & 1u);
  return (u16)(r >> 16);
}

__device__ __forceinline__ void gload_lds16(const void* g, void* l){
  __builtin_amdgcn_global_load_lds((const __attribute__((address_space(1))) void*)g,
                                   (__attribute__((address_space(3))) void*)l, 16, 0, 0);
}

__device__ __forceinline__ f32x4 mfma16(short8 a, short8 b, f32x4 c){
  return __builtin_amdgcn_mfma_f32_16x16x32_bf16(a, b, c, 0, 0, 0);
}

// ---- weight convert + transpose: Wt_bf[n*512+k] = bf16(W[k*512+n]) ----
__global__ __launch_bounds__(256) void wconv_kernel(
    const float* __restrict__ w0, const float* __restrict__ w1,
    const float* __restrict__ w2, const float* __restrict__ w3,
    const float* __restrict__ w4, const float* __restrict__ w5,
    const float* __restrict__ w6, const float* __restrict__ w7,
    u16* __restrict__ out)
{
  int mat = blockIdx.x >> 10;
  const float* w = w0;
  switch (mat){ case 1: w=w1; break; case 2: w=w2; break; case 3: w=w3; break;
                case 4: w=w4; break; case 5: w=w5; break; case 6: w=w6; break;
                case 7: w=w7; break; default: break; }
  int idx = ((blockIdx.x & 1023) << 8) | (int)threadIdx.x;   // n*512 + k
  int n = idx >> 9, k = idx & 511;
  out[((size_t)mat << 18) + idx] = f2bf(w[(size_t)k * 512 + n]);
}

__global__ __launch_bounds__(256) void biascat_kernel(
    const float* __restrict__ bq, const float* __restrict__ bk,
    const float* __restrict__ bv, float* __restrict__ o)
{
  int i = blockIdx.x * 256 + threadIdx.x;      // grid 6 -> 0..1535
  if (i < 512) o[i] = bq[i];
  else if (i < 1024) o[i] = bk[i - 512];
  else o[i] = bv[i - 1024];
}

// ---- layernorm over F=512, two halves with separate params, bf16 out ----
__global__ __launch_bounds__(256) void ln_kernel(
    const float* __restrict__ xa, const float* __restrict__ xb,
    const float* __restrict__ ga, const float* __restrict__ ba,
    const float* __restrict__ gb, const float* __restrict__ bb,
    u16* __restrict__ out)
{
  int row = blockIdx.x;
  const float* x; const float* g; const float* bi;
  if (row < NHALF){ x = xa + (size_t)row * FD; g = ga; bi = ba; }
  else            { x = xb + (size_t)(row - NHALF) * FD; g = gb; bi = bb; }
  int t = threadIdx.x;
  float2 v = ((const float2*)x)[t];
  __shared__ float red[8];
  float s = v.x + v.y;
  #pragma unroll
  for (int o = 32; o; o >>= 1) s += __shfl_xor(s, o, 64);
  if ((t & 63) == 0) red[t >> 6] = s;
  __syncthreads();
  float mu = (red[0] + red[1] + red[2] + red[3]) * (1.0f / 512.0f);
  float d0 = v.x - mu, d1 = v.y - mu;
  float q = d0 * d0 + d1 * d1;
  #pragma unroll
  for (int o = 32; o; o >>= 1) q += __shfl_xor(q, o, 64);
  if ((t & 63) == 0) red[4 + (t >> 6)] = q;
  __syncthreads();
  float var = (red[4] + red[5] + red[6] + red[7]) * (1.0f / 512.0f);
  float rs = rsqrtf(var + 1e-6f);
  out[(size_t)row * FD + 2 * t]     = f2bf(d0 * rs * g[2 * t]     + bi[2 * t]);
  out[(size_t)row * FD + 2 * t + 1] = f2bf(d1 * rs * g[2 * t + 1] + bi[2 * t + 1]);
}

// ---- GEMM: C = A[M,K] @ Bt[N,K]^T + bias (+res), 128x128 tile, BK=32 ----
template<bool RELU, bool OUT_BF16, bool HAS_RES>
__global__ __launch_bounds__(256) void gemm_bt(
    const u16* __restrict__ A,
    const u16* __restrict__ BtLo, const u16* __restrict__ BtHi,
    const float* __restrict__ biasLo, const float* __restrict__ biasHi,
    const float* __restrict__ resLo, const float* __restrict__ resHi,
    void* __restrict__ outp,
    int M, int N, int K, int halfM)
{
  __shared__ __align__(16) u16 lA[128 * 32];
  __shared__ __align__(16) u16 lB[128 * 32];
  int nTN = N >> 7;
  int bm = blockIdx.x / nTN, bn = blockIdx.x - bm * nTN;
  int rowBase = bm << 7, colBase = bn << 7;
  bool lo = rowBase < halfM;
  const u16* Bt = lo ? BtLo : BtHi;
  const float* bias = lo ? biasLo : biasHi;
  const float* res = lo ? resLo : resHi;
  int rowLocalBase = lo ? rowBase : rowBase - halfM;

  int tid = threadIdx.x, wv = tid >> 6, ln = tid & 63;

  f32x4 acc[4][4];
  #pragma unroll
  for (int m = 0; m < 4; m++)
    #pragma unroll
    for (int n = 0; n < 4; n++) acc[m][n] = (f32x4){0.f, 0.f, 0.f, 0.f};

  int off0 = tid * 16, off1 = 4096 + tid * 16;
  int r0 = off0 >> 6, c0 = (off0 & 63) >> 1;
  int r1 = off1 >> 6, c1 = (off1 & 63) >> 1;
  const u16* gA0 = A + (size_t)(rowBase + r0) * K + c0;
  const u16* gA1 = A + (size_t)(rowBase + r1) * K + c1;
  const u16* gB0 = Bt + (size_t)(colBase + r0) * K + c0;
  const u16* gB1 = Bt + (size_t)(colBase + r1) * K + c1;
  char* dA0 = (char*)lA + wv * 1024;
  char* dA1 = (char*)lA + 4096 + wv * 1024;
  char* dB0 = (char*)lB + wv * 1024;
  char* dB1 = (char*)lB + 4096 + wv * 1024;

  int arow = (wv >> 1) << 6, bcol = (wv & 1) << 6;

  for (int kt = 0; kt < K; kt += 32){
    gload_lds16(gA0 + kt, dA0);
    gload_lds16(gA1 + kt, dA1);
    gload_lds16(gB0 + kt, dB0);
    gload_lds16(gB1 + kt, dB1);
    __syncthreads();
    short8 af[4], bfr[4];
    #pragma unroll
    for (int m = 0; m < 4; m++)
      af[m] = *(const short8*)&lA[(arow + (m << 4) + (ln & 15)) * 32 + ((ln >> 4) << 3)];
    #pragma unroll
    for (int n = 0; n < 4; n++)
      bfr[n] = *(const short8*)&lB[(bcol + (n << 4) + (ln & 15)) * 32 + ((ln >> 4) << 3)];
    #pragma unroll
    for (int m = 0; m < 4; m++)
      #pragma unroll
      for (int n = 0; n < 4; n++)
        acc[m][n] = mfma16(af[m], bfr[n], acc[m][n]);
    __syncthreads();
  }

  #pragma unroll
  for (int n = 0; n < 4; n++){
    int col = colBase + bcol + (n << 4) + (ln & 15);
    float bv = bias[col];
    #pragma unroll
    for (int m = 0; m < 4; m++){
      int rowT = arow + (m << 4) + ((ln >> 4) << 2);
      #pragma unroll
      for (int r = 0; r < 4; r++){
        float v = acc[m][n][r] + bv;
        if (RELU) v = fmaxf(v, 0.f);
        if (HAS_RES) v += res[(size_t)(rowLocalBase + rowT + r) * N + col];
        if (OUT_BF16) ((u16*)outp)[(size_t)(rowBase + rowT + r) * N + col] = f2bf(v);
        else ((float*)outp)[(size_t)(rowBase + rowT + r) * N + col] = v;
      }
    }
  }
}

// ---- flash cross-attention: Q tile 64, KV tile 64, D=64, 4 waves ----
__global__ __launch_bounds__(256) void attn_kernel(
    const u16* __restrict__ qkv, u16* __restrict__ fb)
{
  int qt = blockIdx.x;            // 0..31
  int h  = blockIdx.y;            // 0..7
  int z  = blockIdx.z;            // dir*4 + b
  int dir = z >> 2, b = z & 3;
  int qRow0  = dir * NHALF + b * SEQ + qt * 64;
  int kvRow0 = (dir ^ 1) * NHALF + b * SEQ;
  int colQ = h * 64;

  __shared__ __align__(16) u16 lQ[64 * 64];
  __shared__ __align__(16) u16 lK[64 * 64];
  __shared__ __align__(16) u16 lVt[64 * 64];
  __shared__ __align__(16) u16 lP[4][16 * 64];

  int tid = threadIdx.x, wv = tid >> 6, ln = tid & 63;

  #pragma unroll
  for (int inst = 0; inst < 2; inst++){
    int off = inst * 4096 + tid * 16;
    int r = off >> 7, cb = off & 127;
    gload_lds16(qkv + (size_t)(qRow0 + r) * QKVN + colQ + (cb >> 1),
                (char*)lQ + inst * 4096 + wv * 1024);
  }
  __syncthreads();
  short8 qf[2];
  #pragma unroll
  for (int kk = 0; kk < 2; kk++)
    qf[kk] = *(const short8*)&lQ[(wv * 16 + (ln & 15)) * 64 + kk * 32 + ((ln >> 4) << 3)];

  f32x4 acc_o[4];
  #pragma unroll
  for (int nd = 0; nd < 4; nd++) acc_o[nd] = (f32x4){0.f, 0.f, 0.f, 0.f};
  float m_r[4] = {-1e30f, -1e30f, -1e30f, -1e30f};
  float l_r[4] = {0.f, 0.f, 0.f, 0.f};
  const float SCALE = 0.125f;

  for (int kv = 0; kv < SEQ; kv += 64){
    #pragma unroll
    for (int inst = 0; inst < 2; inst++){
      int off = inst * 4096 + tid * 16;
      int r = off >> 7, cb = off & 127;
      gload_lds16(qkv + (size_t)(kvRow0 + kv + r) * QKVN + 512 + colQ + (cb >> 1),
                  (char*)lK + inst * 4096 + wv * 1024);
    }
    {
      int r = tid >> 2, d0 = (tid & 3) * 16;
      const u16* src = qkv + (size_t)(kvRow0 + kv + r) * QKVN + 1024 + colQ + d0;
      short8 v0 = *(const short8*)(src);
      short8 v1 = *(const short8*)(src + 8);
      #pragma unroll
      for (int j = 0; j < 8; j++){
        lVt[(d0 + j) * 64 + r]     = (u16)v0[j];
        lVt[(d0 + 8 + j) * 64 + r] = (u16)v1[j];
      }
    }
    __syncthreads();

    f32x4 s[4];
    #pragma unroll
    for (int n = 0; n < 4; n++) s[n] = (f32x4){0.f, 0.f, 0.f, 0.f};
    #pragma unroll
    for (int kk = 0; kk < 2; kk++){
      #pragma unroll
      for (int n = 0; n < 4; n++){
        short8 kf = *(const short8*)&lK[((n << 4) + (ln & 15)) * 64 + kk * 32 + ((ln >> 4) << 3)];
        s[n] = mfma16(qf[kk], kf, s[n]);
      }
    }

    // online softmax (acc layout: row=(ln>>4)*4+r, col=n*16+(ln&15))
    float alpha[4];
    #pragma unroll
    for (int r = 0; r < 4; r++){
      float m0 = fmaxf(fmaxf(s[0][r], s[1][r]), fmaxf(s[2][r], s[3][r]));
      #pragma unroll
      for (int o = 1; o < 16; o <<= 1) m0 = fmaxf(m0, __shfl_xor(m0, o, 64));
      float mn = fmaxf(m_r[r], m0 * SCALE);
      alpha[r] = __expf(m_r[r] - mn);
      m_r[r] = mn;
    }
    float psum[4] = {0.f, 0.f, 0.f, 0.f};
    #pragma unroll
    for (int n = 0; n < 4; n++)
      #pragma unroll
      for (int r = 0; r < 4; r++){
        float p = __expf(s[n][r] * SCALE - m_r[r]);
        psum[r] += p;
        lP[wv][(((ln >> 4) << 2) + r) * 64 + (n << 4) + (ln & 15)] = f2bf(p);
      }
    #pragma unroll
    for (int r = 0; r < 4; r++){
      float q = psum[r];
      #pragma unroll
      for (int o = 1; o < 16; o <<= 1) q += __shfl_xor(q, o, 64);
      l_r[r] = l_r[r] * alpha[r] + q;
    }
    #pragma unroll
    for (int nd = 0; nd < 4; nd++)
      #pragma unroll
      for (int r = 0; r < 4; r++) acc_o[nd][r] *= alpha[r];

    __syncthreads();   // lP visibility

    #pragma unroll
    for (int kk = 0; kk < 2; kk++){
      short8 pf = *(const short8*)&lP[wv][(ln & 15) * 64 + kk * 32 + ((ln >> 4) << 3)];
      #pragma unroll
      for (int nd = 0; nd < 4; nd++){
        short8 vf = *(const short8*)&lVt[((nd << 4) + (ln & 15)) * 64 + kk * 32 + ((ln >> 4) << 3)];
        acc_o[nd] = mfma16(pf, vf, acc_o[nd]);
      }
    }
    __syncthreads();   // before restaging K/Vt
  }

  #pragma unroll
  for (int nd = 0; nd < 4; nd++)
    #pragma unroll
    for (int r = 0; r < 4; r++){
      int row = qRow0 + wv * 16 + ((ln >> 4) << 2) + r;
      int d   = colQ + (nd << 4) + (ln & 15);
      fb[(size_t)row * FD + d] = f2bf(acc_o[nd][r] / l_r[r]);
    }
}

extern "C" void kernel_launch(void* const* d_in, const int* in_sizes, int n_in,
                              void* d_out, int out_size, void* d_ws, size_t ws_size,
                              hipStream_t stream)
{
  const float* t1   = (const float*)d_in[0];
  const float* t2   = (const float*)d_in[1];
  const float* ln1g = (const float*)d_in[2];
  const float* ln1b = (const float*)d_in[3];
  const float* ln2g = (const float*)d_in[4];
  const float* ln2b = (const float*)d_in[5];
  const float* Wq   = (const float*)d_in[6];
  const float* bq   = (const float*)d_in[7];
  const float* Wk   = (const float*)d_in[8];
  const float* bk   = (const float*)d_in[9];
  const float* Wv   = (const float*)d_in[10];
  const float* bv   = (const float*)d_in[11];
  const float* Wfc  = (const float*)d_in[12];
  const float* bfc  = (const float*)d_in[13];
  const float* f1lg = (const float*)d_in[14];
  const float* f1lb = (const float*)d_in[15];
  const float* W11  = (const float*)d_in[16];
  const float* b11  = (const float*)d_in[17];
  const float* W12  = (const float*)d_in[18];
  const float* b12  = (const float*)d_in[19];
  const float* f2lg = (const float*)d_in[20];
  const float* f2lb = (const float*)d_in[21];
  const float* W21  = (const float*)d_in[22];
  const float* b21  = (const float*)d_in[23];
  const float* W22  = (const float*)d_in[24];
  const float* b22  = (const float*)d_in[25];

  char* ws = (char*)d_ws;
  const size_t MB = 1024 * 1024;
  u16* wt     = (u16*)ws;                  // 8 x [512,512] bf16 (transposed): q,k,v,fc,w11,w12,w21,w22
  u16* tln    = (u16*)(ws + 4 * MB);       // [16384,512]
  u16* qkv    = (u16*)(ws + 20 * MB);      // [16384,1536]
  u16* fb     = (u16*)(ws + 68 * MB);      // [16384,512]
  float* bqkv = (float*)(ws + 84 * MB);    // [1536]
  u16* xln    = tln;                       // reuse
  u16* hb     = qkv;                       // reuse
  float* out  = (float*)d_out;

  wconv_kernel<<<8192, 256, 0, stream>>>(Wq, Wk, Wv, Wfc, W11, W12, W21, W22, wt);
  biascat_kernel<<<6, 256, 0, stream>>>(bq, bk, bv, bqkv);
  ln_kernel<<<NTOT, 256, 0, stream>>>(t1, t2, ln1g, ln1b, ln2g, ln2b, tln);
  gemm_bt<false, true, false><<<1536, 256, 0, stream>>>(
      tln, wt, wt, bqkv, bqkv, nullptr, nullptr, qkv, NTOT, QKVN, FD, NTOT);
  attn_kernel<<<dim3(32, 8, 8), 256, 0, stream>>>(qkv, fb);
  gemm_bt<false, false, true><<<512, 256, 0, stream>>>(
      fb, wt + 3 * 262144, wt + 3 * 262144, bfc, bfc, t1, t2, out, NTOT, FD, FD, NHALF);
  ln_kernel<<<NTOT, 256, 0, stream>>>(out, out + (size_t)NHALF * FD, f1lg, f1lb, f2lg, f2lb, xln);
  gemm_bt<true, true, false><<<512, 256, 0, stream>>>(
      xln, wt + 4 * 262144, wt + 6 * 262144, b11, b21, nullptr, nullptr, hb, NTOT, FD, FD, NHALF);
  gemm_bt<false, false, true><<<512, 256, 0, stream>>>(
      hb, wt + 5 * 262144, wt + 7 * 262144, b12, b22, out, out + (size_t)NHALF * FD, out, NTOT, FD, FD, NHALF);
}

// Round 2
// 387.708 us; speedup vs baseline: 1.2259x; 1.2259x over previous
//
#include <hip/hip_runtime.h>
#include <stdint.h>

#define FD    512
#define SEQ   2048
#define NHALF 8192
#define NTOT  16384
#define QKVN  1536

typedef unsigned short u16;
typedef __attribute__((ext_vector_type(8))) short short8;
typedef __attribute__((ext_vector_type(4))) float f32x4;

__device__ __forceinline__ u16 f2bf(float f){
  union { float f; uint32_t i; } v; v.f = f;
  uint32_t r = v.i + 0x7FFFu + ((v.i >> 16) & 1u);
  return (u16)(r >> 16);
}

__device__ __forceinline__ void gload_lds16(const void* g, void* l){
  __builtin_amdgcn_global_load_lds((const __attribute__((address_space(1))) void*)g,
                                   (__attribute__((address_space(3))) void*)l, 16, 0, 0);
}

__device__ __forceinline__ f32x4 mfma16(short8 a, short8 b, f32x4 c){
  return __builtin_amdgcn_mfma_f32_16x16x32_bf16(a, b, c, 0, 0, 0);
}

// ---- weight convert + transpose: Wt_bf[n*512+k] = bf16(W[k*512+n]) ----
__global__ __launch_bounds__(256) void wconv_kernel(
    const float* __restrict__ w0, const float* __restrict__ w1,
    const float* __restrict__ w2, const float* __restrict__ w3,
    const float* __restrict__ w4, const float* __restrict__ w5,
    const float* __restrict__ w6, const float* __restrict__ w7,
    u16* __restrict__ out)
{
  int mat = blockIdx.x >> 10;
  const float* w = w0;
  switch (mat){ case 1: w=w1; break; case 2: w=w2; break; case 3: w=w3; break;
                case 4: w=w4; break; case 5: w=w5; break; case 6: w=w6; break;
                case 7: w=w7; break; default: break; }
  int idx = ((blockIdx.x & 1023) << 8) | (int)threadIdx.x;   // n*512 + k
  int n = idx >> 9, k = idx & 511;
  out[((size_t)mat << 18) + idx] = f2bf(w[(size_t)k * 512 + n]);
}

__global__ __launch_bounds__(256) void biascat_kernel(
    const float* __restrict__ bq, const float* __restrict__ bk,
    const float* __restrict__ bv, float* __restrict__ o)
{
  int i = blockIdx.x * 256 + threadIdx.x;      // grid 6 -> 0..1535
  if (i < 512) o[i] = bq[i];
  else if (i < 1024) o[i] = bk[i - 512];
  else o[i] = bv[i - 1024];
}

// ---- layernorm over F=512, two halves with separate params, bf16 out ----
__global__ __launch_bounds__(256) void ln_kernel(
    const float* __restrict__ xa, const float* __restrict__ xb,
    const float* __restrict__ ga, const float* __restrict__ ba,
    const float* __restrict__ gb, const float* __restrict__ bb,
    u16* __restrict__ out)
{
  int row = blockIdx.x;
  const float* x; const float* g; const float* bi;
  if (row < NHALF){ x = xa + (size_t)row * FD; g = ga; bi = ba; }
  else            { x = xb + (size_t)(row - NHALF) * FD; g = gb; bi = bb; }
  int t = threadIdx.x;
  float2 v = ((const float2*)x)[t];
  __shared__ float red[8];
  float s = v.x + v.y;
  #pragma unroll
  for (int o = 32; o; o >>= 1) s += __shfl_xor(s, o, 64);
  if ((t & 63) == 0) red[t >> 6] = s;
  __syncthreads();
  float mu = (red[0] + red[1] + red[2] + red[3]) * (1.0f / 512.0f);
  float d0 = v.x - mu, d1 = v.y - mu;
  float q = d0 * d0 + d1 * d1;
  #pragma unroll
  for (int o = 32; o; o >>= 1) q += __shfl_xor(q, o, 64);
  if ((t & 63) == 0) red[4 + (t >> 6)] = q;
  __syncthreads();
  float var = (red[4] + red[5] + red[6] + red[7]) * (1.0f / 512.0f);
  float rs = rsqrtf(var + 1e-6f);
  out[(size_t)row * FD + 2 * t]     = f2bf(d0 * rs * g[2 * t]     + bi[2 * t]);
  out[(size_t)row * FD + 2 * t + 1] = f2bf(d1 * rs * g[2 * t + 1] + bi[2 * t + 1]);
}

// ---- GEMM: C = A[M,K] @ Bt[N,K]^T + bias (+res), 128x128 tile, BK=32 ----
template<bool RELU, bool OUT_BF16, bool HAS_RES>
__global__ __launch_bounds__(256) void gemm_bt(
    const u16* __restrict__ A,
    const u16* __restrict__ BtLo, const u16* __restrict__ BtHi,
    const float* __restrict__ biasLo, const float* __restrict__ biasHi,
    const float* __restrict__ resLo, const float* __restrict__ resHi,
    void* __restrict__ outp,
    int M, int N, int K, int halfM)
{
  __shared__ __align__(16) u16 lA[128 * 32];
  __shared__ __align__(16) u16 lB[128 * 32];
  int nTN = N >> 7;
  int bm = blockIdx.x / nTN, bn = blockIdx.x - bm * nTN;
  int rowBase = bm << 7, colBase = bn << 7;
  bool lo = rowBase < halfM;
  const u16* Bt = lo ? BtLo : BtHi;
  const float* bias = lo ? biasLo : biasHi;
  const float* res = lo ? resLo : resHi;
  int rowLocalBase = lo ? rowBase : rowBase - halfM;

  int tid = threadIdx.x, wv = tid >> 6, ln = tid & 63;

  f32x4 acc[4][4];
  #pragma unroll
  for (int m = 0; m < 4; m++)
    #pragma unroll
    for (int n = 0; n < 4; n++) acc[m][n] = (f32x4){0.f, 0.f, 0.f, 0.f};

  int off0 = tid * 16, off1 = 4096 + tid * 16;
  int r0 = off0 >> 6, c0 = (off0 & 63) >> 1;
  int r1 = off1 >> 6, c1 = (off1 & 63) >> 1;
  const u16* gA0 = A + (size_t)(rowBase + r0) * K + c0;
  const u16* gA1 = A + (size_t)(rowBase + r1) * K + c1;
  const u16* gB0 = Bt + (size_t)(colBase + r0) * K + c0;
  const u16* gB1 = Bt + (size_t)(colBase + r1) * K + c1;
  char* dA0 = (char*)lA + wv * 1024;
  char* dA1 = (char*)lA + 4096 + wv * 1024;
  char* dB0 = (char*)lB + wv * 1024;
  char* dB1 = (char*)lB + 4096 + wv * 1024;

  int arow = (wv >> 1) << 6, bcol = (wv & 1) << 6;

  for (int kt = 0; kt < K; kt += 32){
    gload_lds16(gA0 + kt, dA0);
    gload_lds16(gA1 + kt, dA1);
    gload_lds16(gB0 + kt, dB0);
    gload_lds16(gB1 + kt, dB1);
    __syncthreads();
    short8 af[4], bfr[4];
    #pragma unroll
    for (int m = 0; m < 4; m++)
      af[m] = *(const short8*)&lA[(arow + (m << 4) + (ln & 15)) * 32 + ((ln >> 4) << 3)];
    #pragma unroll
    for (int n = 0; n < 4; n++)
      bfr[n] = *(const short8*)&lB[(bcol + (n << 4) + (ln & 15)) * 32 + ((ln >> 4) << 3)];
    #pragma unroll
    for (int m = 0; m < 4; m++)
      #pragma unroll
      for (int n = 0; n < 4; n++)
        acc[m][n] = mfma16(af[m], bfr[n], acc[m][n]);
    __syncthreads();
  }

  #pragma unroll
  for (int n = 0; n < 4; n++){
    int col = colBase + bcol + (n << 4) + (ln & 15);
    float bv = bias[col];
    #pragma unroll
    for (int m = 0; m < 4; m++){
      int rowT = arow + (m << 4) + ((ln >> 4) << 2);
      #pragma unroll
      for (int r = 0; r < 4; r++){
        float v = acc[m][n][r] + bv;
        if (RELU) v = fmaxf(v, 0.f);
        if (HAS_RES) v += res[(size_t)(rowLocalBase + rowT + r) * N + col];
        if (OUT_BF16) ((u16*)outp)[(size_t)(rowBase + rowT + r) * N + col] = f2bf(v);
        else ((float*)outp)[(size_t)(rowBase + rowT + r) * N + col] = v;
      }
    }
  }
}

// ---- flash cross-attention, swizzled LDS + double-buffer, 1 barrier/tile ----
// Swizzles:
//   K/Q tiles (64x64 u16): byte ^= ((row&7)<<4)   via pre-swizzled gload_lds src
//   Vt tile:               byte ^= ((row&7)<<4) ^ (((row>>4)&3)<<5)
//   lP tile (16x64/wave):  byte ^= ((row&7)<<4)
__global__ __launch_bounds__(256) void attn_kernel(
    const u16* __restrict__ qkv, u16* __restrict__ fb)
{
  int qt = blockIdx.x;            // 0..31
  int h  = blockIdx.y;            // 0..7
  int z  = blockIdx.z;            // dir*4 + b
  int dir = z >> 2, b = z & 3;
  int qRow0  = dir * NHALF + b * SEQ + qt * 64;
  int kvRow0 = (dir ^ 1) * NHALF + b * SEQ;
  int colQ = h * 64;

  __shared__ __align__(16) u16 lK[2][64 * 64];
  __shared__ __align__(16) u16 lVt[2][64 * 64];
  __shared__ __align__(16) u16 lP[4][16 * 64];

  int tid = threadIdx.x, wv = tid >> 6, ln = tid & 63;
  int g = ln >> 4, lo = ln & 15;

  // staging geometry (per lane): two 16B chunks, rows r0 / r0+32, swizzled src slot
  int srow = tid >> 3;                       // 0..31
  int soff = ((tid & 7) ^ (srow & 7)) * 8;   // u16 offset within row (pre-swizzled)

  // V staging geometry
  int vr  = tid >> 2;                        // k row 0..63
  int vd0 = (tid & 3) * 16;                  // d block base
  int vdi = (tid & 3) << 4;                  // == vd0; (drow>>4)&3 = tid&3

  const float CEXP = 0.125f * 1.44269504f;

  // frag-read swizzled column offsets (u16 index within row)
  int ca0 = ((0 * 32 + g * 8) ^ ((lo & 7) << 3));   // kk=0
  int ca1 = ((1 * 32 + g * 8) ^ ((lo & 7) << 3));   // kk=1

  // ---- prologue: Q -> lK[0], read q frags ----
  {
    const u16* src = qkv + (size_t)(qRow0 + srow) * QKVN + colQ + soff;
    gload_lds16(src, (char*)lK[0] + wv * 1024);
    const u16* src2 = qkv + (size_t)(qRow0 + 32 + srow) * QKVN + colQ + soff;
    gload_lds16(src2, (char*)lK[0] + 4096 + wv * 1024);
  }
  __syncthreads();
  short8 qf[2];
  qf[0] = *(const short8*)&lK[0][(wv * 16 + lo) * 64 + ca0];
  qf[1] = *(const short8*)&lK[0][(wv * 16 + lo) * 64 + ca1];
  __syncthreads();

  // ---- stage K(0), Vt(0) ----
  {
    const u16* src = qkv + (size_t)(kvRow0 + srow) * QKVN + 512 + colQ + soff;
    gload_lds16(src, (char*)lK[0] + wv * 1024);
    const u16* src2 = qkv + (size_t)(kvRow0 + 32 + srow) * QKVN + 512 + colQ + soff;
    gload_lds16(src2, (char*)lK[0] + 4096 + wv * 1024);
    const u16* vsrc = qkv + (size_t)(kvRow0 + vr) * QKVN + 1024 + colQ + vd0;
    short8 v0 = *(const short8*)vsrc;
    short8 v1 = *(const short8*)(vsrc + 8);
    #pragma unroll
    for (int jj = 0; jj < 16; jj++){
      int drow = vd0 + jj;
      u16 val = (u16)(jj < 8 ? v0[jj] : v1[jj - 8]);
      lVt[0][drow * 64 + (vr ^ ((drow & 7) << 3) ^ (vdi))] = val;
    }
  }
  __syncthreads();

  f32x4 acc_o[4];
  #pragma unroll
  for (int nd = 0; nd < 4; nd++) acc_o[nd] = (f32x4){0.f, 0.f, 0.f, 0.f};
  f32x4 acc_l = (f32x4){0.f, 0.f, 0.f, 0.f};
  float m_r[4] = {-1e30f, -1e30f, -1e30f, -1e30f};

  short8 ones;
  #pragma unroll
  for (int j = 0; j < 8; j++) ones[j] = (short)0x3F80;

  for (int t = 0; t < 32; t++){
    int cur = t & 1, nxt = cur ^ 1;
    short8 nv0, nv1;
    if (t < 31){
      int kvr = kvRow0 + (t + 1) * 64;
      const u16* src = qkv + (size_t)(kvr + srow) * QKVN + 512 + colQ + soff;
      gload_lds16(src, (char*)lK[nxt] + wv * 1024);
      const u16* src2 = qkv + (size_t)(kvr + 32 + srow) * QKVN + 512 + colQ + soff;
      gload_lds16(src2, (char*)lK[nxt] + 4096 + wv * 1024);
      const u16* vsrc = qkv + (size_t)(kvr + vr) * QKVN + 1024 + colQ + vd0;
      nv0 = *(const short8*)vsrc;
      nv1 = *(const short8*)(vsrc + 8);
    }

    // QK^T
    f32x4 s[4];
    #pragma unroll
    for (int n = 0; n < 4; n++) s[n] = (f32x4){0.f, 0.f, 0.f, 0.f};
    #pragma unroll
    for (int n = 0; n < 4; n++){
      short8 kf0 = *(const short8*)&lK[cur][(n * 16 + lo) * 64 + ca0];
      short8 kf1 = *(const short8*)&lK[cur][(n * 16 + lo) * 64 + ca1];
      s[n] = mfma16(qf[0], kf0, s[n]);
      s[n] = mfma16(qf[1], kf1, s[n]);
    }

    // online softmax; write P to lP (per-wave, no barrier needed)
    #pragma unroll
    for (int r = 0; r < 4; r++){
      float m0 = fmaxf(fmaxf(s[0][r], s[1][r]), fmaxf(s[2][r], s[3][r]));
      #pragma unroll
      for (int o = 1; o < 16; o <<= 1) m0 = fmaxf(m0, __shfl_xor(m0, o, 64));
      float mn = fmaxf(m_r[r], m0);
      float a = exp2f((m_r[r] - mn) * CEXP);
      m_r[r] = mn;
      float mc = mn * CEXP;
      int qrow = g * 4 + r;
      int rsw = (qrow & 7) << 3;
      #pragma unroll
      for (int n = 0; n < 4; n++){
        float p = exp2f(fmaf(s[n][r], CEXP, -mc));
        lP[wv][qrow * 64 + ((n * 16 + lo) ^ rsw)] = f2bf(p);
      }
      acc_l[r] *= a;
      #pragma unroll
      for (int nd = 0; nd < 4; nd++) acc_o[nd][r] *= a;
    }

    // stage Vt(t+1)
    if (t < 31){
      #pragma unroll
      for (int jj = 0; jj < 16; jj++){
        int drow = vd0 + jj;
        u16 val = (u16)(jj < 8 ? nv0[jj] : nv1[jj - 8]);
        lVt[nxt][drow * 64 + (vr ^ ((drow & 7) << 3) ^ (vdi))] = val;
      }
    }

    // PV + row-sum via ones-MFMA
    #pragma unroll
    for (int kk = 0; kk < 2; kk++){
      int cp = kk ? ca1 : ca0;
      short8 pf = *(const short8*)&lP[wv][lo * 64 + cp];
      acc_l = mfma16(pf, ones, acc_l);
      #pragma unroll
      for (int nd = 0; nd < 4; nd++){
        short8 vf = *(const short8*)&lVt[cur][(nd * 16 + lo) * 64 + (cp ^ (nd << 4))];
        acc_o[nd] = mfma16(pf, vf, acc_o[nd]);
      }
    }

    __syncthreads();
  }

  #pragma unroll
  for (int nd = 0; nd < 4; nd++)
    #pragma unroll
    for (int r = 0; r < 4; r++){
      int row = qRow0 + wv * 16 + g * 4 + r;
      int d   = colQ + (nd << 4) + lo;
      fb[(size_t)row * FD + d] = f2bf(acc_o[nd][r] / acc_l[r]);
    }
}

extern "C" void kernel_launch(void* const* d_in, const int* in_sizes, int n_in,
                              void* d_out, int out_size, void* d_ws, size_t ws_size,
                              hipStream_t stream)
{
  const float* t1   = (const float*)d_in[0];
  const float* t2   = (const float*)d_in[1];
  const float* ln1g = (const float*)d_in[2];
  const float* ln1b = (const float*)d_in[3];
  const float* ln2g = (const float*)d_in[4];
  const float* ln2b = (const float*)d_in[5];
  const float* Wq   = (const float*)d_in[6];
  const float* bq   = (const float*)d_in[7];
  const float* Wk   = (const float*)d_in[8];
  const float* bk   = (const float*)d_in[9];
  const float* Wv   = (const float*)d_in[10];
  const float* bv   = (const float*)d_in[11];
  const float* Wfc  = (const float*)d_in[12];
  const float* bfc  = (const float*)d_in[13];
  const float* f1lg = (const float*)d_in[14];
  const float* f1lb = (const float*)d_in[15];
  const float* W11  = (const float*)d_in[16];
  const float* b11  = (const float*)d_in[17];
  const float* W12  = (const float*)d_in[18];
  const float* b12  = (const float*)d_in[19];
  const float* f2lg = (const float*)d_in[20];
  const float* f2lb = (const float*)d_in[21];
  const float* W21  = (const float*)d_in[22];
  const float* b21  = (const float*)d_in[23];
  const float* W22  = (const float*)d_in[24];
  const float* b22  = (const float*)d_in[25];

  char* ws = (char*)d_ws;
  const size_t MB = 1024 * 1024;
  u16* wt     = (u16*)ws;                  // 8 x [512,512] bf16 (transposed): q,k,v,fc,w11,w12,w21,w22
  u16* tln    = (u16*)(ws + 4 * MB);       // [16384,512]
  u16* qkv    = (u16*)(ws + 20 * MB);      // [16384,1536]
  u16* fb     = (u16*)(ws + 68 * MB);      // [16384,512]
  float* bqkv = (float*)(ws + 84 * MB);    // [1536]
  u16* xln    = tln;                       // reuse
  u16* hb     = qkv;                       // reuse
  float* out  = (float*)d_out;

  wconv_kernel<<<8192, 256, 0, stream>>>(Wq, Wk, Wv, Wfc, W11, W12, W21, W22, wt);
  biascat_kernel<<<6, 256, 0, stream>>>(bq, bk, bv, bqkv);
  ln_kernel<<<NTOT, 256, 0, stream>>>(t1, t2, ln1g, ln1b, ln2g, ln2b, tln);
  gemm_bt<false, true, false><<<1536, 256, 0, stream>>>(
      tln, wt, wt, bqkv, bqkv, nullptr, nullptr, qkv, NTOT, QKVN, FD, NTOT);
  attn_kernel<<<dim3(32, 8, 8), 256, 0, stream>>>(qkv, fb);
  gemm_bt<false, false, true><<<512, 256, 0, stream>>>(
      fb, wt + 3 * 262144, wt + 3 * 262144, bfc, bfc, t1, t2, out, NTOT, FD, FD, NHALF);
  ln_kernel<<<NTOT, 256, 0, stream>>>(out, out + (size_t)NHALF * FD, f1lg, f1lb, f2lg, f2lb, xln);
  gemm_bt<true, true, false><<<512, 256, 0, stream>>>(
      xln, wt + 4 * 262144, wt + 6 * 262144, b11, b21, nullptr, nullptr, hb, NTOT, FD, FD, NHALF);
  gemm_bt<false, false, true><<<512, 256, 0, stream>>>(
      hb, wt + 5 * 262144, wt + 7 * 262144, b12, b22, out, out + (size_t)NHALF * FD, out, NTOT, FD, FD, NHALF);
}